// Round 17
// baseline (126.844 us; speedup 1.0000x reference)
//
#include <hip/hip_runtime.h>

#define BB 2
#define NN 16384
#define KK 4096
#define CC 128
#define SS 32
#define BKK (BB * KK)

typedef float vfloat4 __attribute__((ext_vector_type(4)));

// ---------------------------------------------------------------------------
// Kernel A: transpose features [B][C][N] -> [B][N][C] + fused xyzw prep.
// float4-vectorized on BOTH global sides. UNCHANGED from round 16 (passed).
// ---------------------------------------------------------------------------
__global__ __launch_bounds__(256) void transpose_prep_kernel(
    const float* __restrict__ feat, const float* __restrict__ xyz,
    float* __restrict__ feat_t, float* __restrict__ xyzw)
{
    __shared__ float tile[64][133];
    const int b  = blockIdx.x >> 8;          // NN/64 = 256 tiles per batch
    const int n0 = (blockIdx.x & 255) * 64;
    const int t  = threadIdx.x;

    if (t < 64) {
        const int i = b * NN + n0 + t;
        const float* p = xyz + (size_t)i * 3;
        const float x = p[0], y = p[1], z = p[2];
        const float pp = __fadd_rn(__fadd_rn(__fmul_rn(x, x), __fmul_rn(y, y)),
                                   __fmul_rn(z, z));
        vfloat4 v = {x, y, z, pp};
        *(vfloat4*)(xyzw + (size_t)i * 4) = v;
    }

#pragma unroll
    for (int i = 0; i < 8; ++i) {
        const int li = i * 256 + t;
        const int c  = li >> 4;
        const int n4 = (li & 15) * 4;
        const vfloat4 v = *(const vfloat4*)(feat + ((size_t)b * CC + c) * NN + n0 + n4);
        tile[n4 + 0][c] = v.x;
        tile[n4 + 1][c] = v.y;
        tile[n4 + 2][c] = v.z;
        tile[n4 + 3][c] = v.w;
    }
    __syncthreads();

#pragma unroll
    for (int i = 0; i < 8; ++i) {
        const int li = i * 256 + t;
        const int n  = li >> 5;
        const int c4 = (li & 31) * 4;
        vfloat4 v;
        v.x = tile[n][c4 + 0];
        v.y = tile[n][c4 + 1];
        v.z = tile[n][c4 + 2];
        v.w = tile[n][c4 + 3];
        *(vfloat4*)(feat_t + ((size_t)(b * NN + n0 + n)) * CC + c4) = v;
    }
}

// ---------------------------------------------------------------------------
// Kernel S: query sort. UNCHANGED from round 16 (2-level batch-major key:
// bucket = (b<<6) | min(63, |q|^2*8); quads of sorted order never straddle
// batches since 4096 % 4 == 0). Output-order-invariant.
// ---------------------------------------------------------------------------
__global__ __launch_bounds__(1024) void qsort_kernel(
    const float* __restrict__ new_xyz,   // [B][K][3]
    int* __restrict__ qmap)              // [BKK]
{
    __shared__ int hist[128];
    __shared__ int base[128];
    __shared__ unsigned char bk[BKK];    // 8 KB

    const int t = threadIdx.x;
    if (t < 128) hist[t] = 0;
    __syncthreads();

#pragma unroll
    for (int c = 0; c < BKK / 1024; ++c) {
        const int q = c * 1024 + t;
        const int b = q >> 12;                       // K = 4096
        const float* p = new_xyz + (size_t)q * 3;
        const float qq = p[0] * p[0] + p[1] * p[1] + p[2] * p[2];
        int bkt = (int)(qq * 8.0f);
        bkt = bkt > 63 ? 63 : bkt;
        bkt |= (b << 6);                             // batch-major
        bk[q] = (unsigned char)bkt;
        atomicAdd(&hist[bkt], 1);
    }
    __syncthreads();

    if (t == 0) {
        int s = 0;
#pragma unroll
        for (int i = 0; i < 128; ++i) { base[i] = s; s += hist[i]; }
    }
    __syncthreads();

#pragma unroll
    for (int c = 0; c < BKK / 1024; ++c) {
        const int q = c * 1024 + t;
        const int pos = atomicAdd(&base[bk[q]], 1);
        qmap[pos] = q;
    }
}

// ---------------------------------------------------------------------------
// Kernel B: ball query v6 — IN-WAVE 4-query sharing, zero barriers.
// Each wave owns 4 sorted-adjacent queries (batch-uniform quad). Per chunk
// of 64 points each lane loads its point ONCE (dwordx4, 1-deep prefetch) and
// tests all 4 queries: L2 read traffic /4 vs per-wave-per-query, without
// v5's barrier/staging overhead (round 16: -12us regression, reverted).
// Wave exits when all 4 done (sorted => near-equal scan lengths, round-14-
// verified). All per-query state in fully-unrolled register arrays.
// Float exprs EXACTLY match reference (no fma, left-assoc) -> absmax 0.0.
// ---------------------------------------------------------------------------
__global__ __launch_bounds__(256) void ball_query_kernel(
    const float* __restrict__ xyzw,      // [B][N][4]
    const float* __restrict__ new_xyz,   // [B][K][3]
    const int* __restrict__ qmap,        // [BKK]
    int* __restrict__ idx_buf)           // [BKK][S]
{
    const int wave = threadIdx.x >> 6;
    const int lane = threadIdx.x & 63;
    const int wq   = (blockIdx.x * 4 + wave) * 4;    // first of this wave's 4

    const float R2 = (float)(0.4 * 0.4);

    int   qi[4];
    float qx[4], qy[4], qz[4], qq[4];
    int*  out[4];
#pragma unroll
    for (int j = 0; j < 4; ++j) {
        qi[j] = qmap[wq + j];
        const float* q = new_xyz + (size_t)qi[j] * 3;
        qx[j] = q[0]; qy[j] = q[1]; qz[j] = q[2];
        qq[j] = __fadd_rn(__fadd_rn(__fmul_rn(qx[j], qx[j]), __fmul_rn(qy[j], qy[j])),
                          __fmul_rn(qz[j], qz[j]));
        out[j] = idx_buf + (size_t)qi[j] * SS;
    }
    const int b = qi[0] >> 12;           // batch-uniform quad (batch-major sort)
    const vfloat4* xw = (const vfloat4*)xyzw + (size_t)b * NN;

    int cnt[4]   = {0, 0, 0, 0};
    int first[4] = {-1, -1, -1, -1};

    vfloat4 cur = xw[lane];
    for (int base = 0; base < NN; base += 64) {
        const int nb = (base + 64 < NN) ? base + 64 : 0;   // clamp; values unused
        const vfloat4 nxt = xw[nb + lane];

        bool done = true;
#pragma unroll
        for (int j = 0; j < 4; ++j) {
            if (cnt[j] < SS) {           // wave-uniform branch
                const float dot = __fadd_rn(
                    __fadd_rn(__fmul_rn(qx[j], cur.x), __fmul_rn(qy[j], cur.y)),
                    __fmul_rn(qz[j], cur.z));
                const float d2 = __fsub_rn(__fadd_rn(qq[j], cur.w),
                                           __fmul_rn(2.0f, dot));
                const bool inball = d2 < R2;
                const unsigned long long m = __ballot(inball);
                if (m) {
                    if (first[j] < 0) first[j] = base + (int)__builtin_ctzll(m);
                    if (inball) {
                        const int pos = cnt[j] + __popcll(m & ((1ull << lane) - 1ull));
                        if (pos < SS) out[j][pos] = base + lane;
                    }
                    cnt[j] += __popcll(m);
                }
            }
            done = done && (cnt[j] >= SS);
        }
        if (done) break;                 // wave-uniform
        cur = nxt;
    }

#pragma unroll
    for (int j = 0; j < 4; ++j) {
        const int fill = (first[j] < 0) ? 0 : first[j];
        if (lane < SS && lane >= cnt[j]) out[j][lane] = fill;
    }
}

// ---------------------------------------------------------------------------
// Kernel C: grouping. UNCHANGED single-copy form (G~7us gather + W~24us
// stores, 0 bank conflicts — validated round 10).
// ---------------------------------------------------------------------------
__global__ __launch_bounds__(256) void group_kernel(
    const float* __restrict__ xyzw,      // [B][N][4]
    const float* __restrict__ new_xyz,   // [B][K][3]
    const float* __restrict__ feat_t,    // [B][N][C]
    const int*   __restrict__ idx_buf,   // [B*K][S]
    float* __restrict__ out)             // [B][3][K][S] ++ [B][C][K][S]
{
    __shared__ float tile[SS * CC];      // 32 rows x 512B, linear, chunk-swizzled
    __shared__ float txyz[3][SS];

    const int t    = threadIdx.x;
    const int l    = t & 63;
    const int w    = t >> 6;             // wave 0..3
    const int bk   = blockIdx.x;
    const int b    = bk >> 12;
    const int k    = bk & (KK - 1);
    const int half = l >> 5;             // 0..1
    const int cl   = l & 31;             // chunk slot within row

#pragma unroll
    for (int p = 0; p < 4; ++p) {
        const int r = 8 * w + 2 * p;                 // wave-uniform row base
        const int s = r + half;
        const int n = idx_buf[bk * SS + s];
        const int chunk = cl ^ ((s >> 2) & 7);
        const float* src = feat_t + ((size_t)(b * NN + n)) * CC + 4 * chunk;
        __builtin_amdgcn_global_load_lds(
            (const __attribute__((address_space(1))) void*)src,
            (__attribute__((address_space(3))) void*)(tile + r * CC),
            16, 0, 0);
    }

    if (t < SS) {
        const int n = idx_buf[bk * SS + t];
        const float* q = new_xyz + (size_t)bk * 3;
        const vfloat4 wv = *((const vfloat4*)xyzw + (size_t)b * NN + n);
        txyz[0][t] = (wv.x - q[0]) / 0.4f;
        txyz[1][t] = (wv.y - q[1]) / 0.4f;
        txyz[2][t] = (wv.z - q[2]) / 0.4f;
    }

    __syncthreads();   // drains vmcnt(0): all DMAs + txyz visible

    float* out_xyz  = out;
    float* out_feat = out + (size_t)BB * 3 * KK * SS;

    const int sq = t & 7;
    const int c0 = t >> 3;               // 0..31
#pragma unroll
    for (int p = 0; p < 4; ++p) {
        const int c  = c0 + 32 * p;
        const int co = (((c >> 2) ^ sq) << 2) + (c & 3);   // un-swizzled col
        vfloat4 v;
        v.x = tile[(4 * sq + 0) * CC + co];
        v.y = tile[(4 * sq + 1) * CC + co];
        v.z = tile[(4 * sq + 2) * CC + co];
        v.w = tile[(4 * sq + 3) * CC + co];
        __builtin_nontemporal_store(
            v, (vfloat4*)(out_feat + (((size_t)(b * CC + c) * KK + k) * SS + 4 * sq)));
    }

    if (t < 24) {
        const int d   = t >> 3;
        const int sq2 = t & 7;
        const vfloat4 v = *(vfloat4*)&txyz[d][4 * sq2];
        __builtin_nontemporal_store(
            v, (vfloat4*)(out_xyz + (((size_t)(b * 3 + d) * KK + k) * SS + 4 * sq2)));
    }
}

extern "C" void kernel_launch(void* const* d_in, const int* in_sizes, int n_in,
                              void* d_out, int out_size, void* d_ws, size_t ws_size,
                              hipStream_t stream) {
    const float* xyz     = (const float*)d_in[0];   // [2][16384][3]
    const float* new_xyz = (const float*)d_in[1];   // [2][4096][3]
    const float* feat    = (const float*)d_in[2];   // [2][128][16384]
    float* out = (float*)d_out;

    // Workspace: idx_buf 1MB | xyzw 0.5MB | feat_t 16MB | qmap 32KB
    int*   idx_buf = (int*)d_ws;
    float* xyzw    = (float*)((char*)d_ws + (1 << 20));
    float* feat_t  = (float*)((char*)d_ws + (1 << 20) + (512 << 10));
    int*   qmap    = (int*)((char*)d_ws + (1 << 20) + (512 << 10) + (CC * NN * BB) * 4);

    transpose_prep_kernel<<<dim3(BB * (NN / 64)), dim3(256), 0, stream>>>(
        feat, xyz, feat_t, xyzw);

    qsort_kernel<<<dim3(1), dim3(1024), 0, stream>>>(new_xyz, qmap);

    // 4 queries per wave, 4 waves per block -> 16 queries/block, 512 blocks.
    ball_query_kernel<<<dim3(BKK / 16), dim3(256), 0, stream>>>(
        xyzw, new_xyz, qmap, idx_buf);

    group_kernel<<<dim3(BKK), dim3(256), 0, stream>>>(
        xyzw, new_xyz, feat_t, idx_buf, out);
}

// Round 19
// 92.097 us; speedup vs baseline: 1.3773x; 1.3773x over previous
//
#include <hip/hip_runtime.h>

#define BB 2
#define NN 16384
#define KK 4096
#define CC 128
#define SS 32
#define BKK (BB * KK)

typedef float vfloat4 __attribute__((ext_vector_type(4)));

// ---------------------------------------------------------------------------
// Kernel A: transpose features [B][C][N] -> [B][N][C] + fused xyzw prep.
// float4-vectorized on BOTH global sides (verified round 16/17).
// ---------------------------------------------------------------------------
__global__ __launch_bounds__(256) void transpose_prep_kernel(
    const float* __restrict__ feat, const float* __restrict__ xyz,
    float* __restrict__ feat_t, float* __restrict__ xyzw)
{
    __shared__ float tile[64][133];
    const int b  = blockIdx.x >> 8;          // NN/64 = 256 tiles per batch
    const int n0 = (blockIdx.x & 255) * 64;
    const int t  = threadIdx.x;

    if (t < 64) {
        const int i = b * NN + n0 + t;
        const float* p = xyz + (size_t)i * 3;
        const float x = p[0], y = p[1], z = p[2];
        const float pp = __fadd_rn(__fadd_rn(__fmul_rn(x, x), __fmul_rn(y, y)),
                                   __fmul_rn(z, z));
        vfloat4 v = {x, y, z, pp};
        *(vfloat4*)(xyzw + (size_t)i * 4) = v;
    }

#pragma unroll
    for (int i = 0; i < 8; ++i) {
        const int li = i * 256 + t;
        const int c  = li >> 4;
        const int n4 = (li & 15) * 4;
        const vfloat4 v = *(const vfloat4*)(feat + ((size_t)b * CC + c) * NN + n0 + n4);
        tile[n4 + 0][c] = v.x;
        tile[n4 + 1][c] = v.y;
        tile[n4 + 2][c] = v.z;
        tile[n4 + 3][c] = v.w;
    }
    __syncthreads();

#pragma unroll
    for (int i = 0; i < 8; ++i) {
        const int li = i * 256 + t;
        const int n  = li >> 5;
        const int c4 = (li & 31) * 4;
        vfloat4 v;
        v.x = tile[n][c4 + 0];
        v.y = tile[n][c4 + 1];
        v.z = tile[n][c4 + 2];
        v.w = tile[n][c4 + 3];
        *(vfloat4*)(feat_t + ((size_t)(b * NN + n0 + n)) * CC + c4) = v;
    }
}

// ---------------------------------------------------------------------------
// Kernel S: query sort — 2-level batch-major key (verified round 16):
// bucket = (b<<6) | min(63, |q|^2*8). All batch-0 queries precede batch-1;
// 4096 % 4 == 0 -> every ball block's 4 waves share one batch (same xw base
// -> same chunk addresses -> L1 reuse) AND similar scan lengths.
// Output-order-invariant; key fast-math affects grouping quality only.
// ---------------------------------------------------------------------------
__global__ __launch_bounds__(1024) void qsort_kernel(
    const float* __restrict__ new_xyz,   // [B][K][3]
    int* __restrict__ qmap)              // [BKK]
{
    __shared__ int hist[128];
    __shared__ int base[128];
    __shared__ unsigned char bk[BKK];    // 8 KB

    const int t = threadIdx.x;
    if (t < 128) hist[t] = 0;
    __syncthreads();

#pragma unroll
    for (int c = 0; c < BKK / 1024; ++c) {
        const int q = c * 1024 + t;
        const int b = q >> 12;                       // K = 4096
        const float* p = new_xyz + (size_t)q * 3;
        const float qq = p[0] * p[0] + p[1] * p[1] + p[2] * p[2];
        int bkt = (int)(qq * 8.0f);
        bkt = bkt > 63 ? 63 : bkt;
        bkt |= (b << 6);                             // batch-major
        bk[q] = (unsigned char)bkt;
        atomicAdd(&hist[bkt], 1);
    }
    __syncthreads();

    if (t == 0) {
        int s = 0;
#pragma unroll
        for (int i = 0; i < 128; ++i) { base[i] = s; s += hist[i]; }
    }
    __syncthreads();

#pragma unroll
    for (int c = 0; c < BKK / 1024; ++c) {
        const int q = c * 1024 + t;
        const int pos = atomicAdd(&base[bk[q]], 1);
        qmap[pos] = q;
    }
}

// ---------------------------------------------------------------------------
// Kernel B: ball query — CHAMPION round-14 body verbatim (per-wave 256-pt
// scan, 1-iter prefetch, qmap indexing; ~34us, absmax 0.0). v5 (LDS-share,
// r16: +5us) and v6 (4q/wave, r17: +47us, 12% occ) both REVERTED — ball
// needs all 8192 waves. The 2-level sort key now makes block-mates
// batch-uniform -> same chunk addresses -> potential free L1 reuse.
// Float exprs EXACTLY match reference. Do not alter.
// ---------------------------------------------------------------------------
__global__ __launch_bounds__(256) void ball_query_kernel(
    const float* __restrict__ xyzw,      // [B][N][4]
    const float* __restrict__ new_xyz,   // [B][K][3]
    const int* __restrict__ qmap,        // [BKK]
    int* __restrict__ idx_buf)           // [BKK][S]
{
    const int wave = threadIdx.x >> 6;
    const int lane = threadIdx.x & 63;
    const int qi   = qmap[blockIdx.x * 4 + wave];
    const int b    = qi >> 12;                   // K = 4096
    const int k    = qi & (KK - 1);

    const float R2 = (float)(0.4 * 0.4);

    const float* q = new_xyz + (size_t)(b * KK + k) * 3;
    const float qx = q[0], qy = q[1], qz = q[2];
    const float qq = __fadd_rn(__fadd_rn(__fmul_rn(qx, qx), __fmul_rn(qy, qy)),
                               __fmul_rn(qz, qz));

    const vfloat4* xw = (const vfloat4*)xyzw + (size_t)b * NN;
    int* out = idx_buf + (size_t)qi * SS;

    int cnt = 0;
    int first = -1;

    auto process = [&](int base, vfloat4 v) {
        const float dot = __fadd_rn(__fadd_rn(__fmul_rn(qx, v.x), __fmul_rn(qy, v.y)),
                                    __fmul_rn(qz, v.z));
        const float d2 = __fsub_rn(__fadd_rn(qq, v.w), __fmul_rn(2.0f, dot));
        const bool inball = d2 < R2;
        const unsigned long long mask = __ballot(inball);
        if (mask) {
            if (first < 0) first = base + (int)__builtin_ctzll(mask);
            if (inball) {
                const int pos = cnt + __popcll(mask & ((1ull << lane) - 1ull));
                if (pos < SS) out[pos] = base + lane;
            }
            cnt += __popcll(mask);
        }
    };

    vfloat4 v0 = xw[lane];
    vfloat4 v1 = xw[64 + lane];
    vfloat4 v2 = xw[128 + lane];
    vfloat4 v3 = xw[192 + lane];

    for (int base = 0; base < NN; base += 256) {
        const int nb = (base + 256 < NN) ? base + 256 : 0;   // clamp; unused vals
        vfloat4 u0 = xw[nb + lane];
        vfloat4 u1 = xw[nb + 64 + lane];
        vfloat4 u2 = xw[nb + 128 + lane];
        vfloat4 u3 = xw[nb + 192 + lane];

        process(base, v0);
        process(base + 64, v1);
        process(base + 128, v2);
        process(base + 192, v3);
        if (cnt >= SS) break;

        v0 = u0; v1 = u1; v2 = u2; v3 = u3;
    }

    const int fill = (first < 0) ? 0 : first;
    if (lane < SS && lane >= cnt) out[lane] = fill;
}

// ---------------------------------------------------------------------------
// Kernel C: grouping. UNCHANGED single-copy form (G~7us gather + W~24us
// stores, 0 bank conflicts — validated round 10).
// ---------------------------------------------------------------------------
__global__ __launch_bounds__(256) void group_kernel(
    const float* __restrict__ xyzw,      // [B][N][4]
    const float* __restrict__ new_xyz,   // [B][K][3]
    const float* __restrict__ feat_t,    // [B][N][C]
    const int*   __restrict__ idx_buf,   // [B*K][S]
    float* __restrict__ out)             // [B][3][K][S] ++ [B][C][K][S]
{
    __shared__ float tile[SS * CC];      // 32 rows x 512B, linear, chunk-swizzled
    __shared__ float txyz[3][SS];

    const int t    = threadIdx.x;
    const int l    = t & 63;
    const int w    = t >> 6;             // wave 0..3
    const int bk   = blockIdx.x;
    const int b    = bk >> 12;
    const int k    = bk & (KK - 1);
    const int half = l >> 5;             // 0..1
    const int cl   = l & 31;             // chunk slot within row

#pragma unroll
    for (int p = 0; p < 4; ++p) {
        const int r = 8 * w + 2 * p;                 // wave-uniform row base
        const int s = r + half;
        const int n = idx_buf[bk * SS + s];
        const int chunk = cl ^ ((s >> 2) & 7);
        const float* src = feat_t + ((size_t)(b * NN + n)) * CC + 4 * chunk;
        __builtin_amdgcn_global_load_lds(
            (const __attribute__((address_space(1))) void*)src,
            (__attribute__((address_space(3))) void*)(tile + r * CC),
            16, 0, 0);
    }

    if (t < SS) {
        const int n = idx_buf[bk * SS + t];
        const float* q = new_xyz + (size_t)bk * 3;
        const vfloat4 wv = *((const vfloat4*)xyzw + (size_t)b * NN + n);
        txyz[0][t] = (wv.x - q[0]) / 0.4f;
        txyz[1][t] = (wv.y - q[1]) / 0.4f;
        txyz[2][t] = (wv.z - q[2]) / 0.4f;
    }

    __syncthreads();   // drains vmcnt(0): all DMAs + txyz visible

    float* out_xyz  = out;
    float* out_feat = out + (size_t)BB * 3 * KK * SS;

    const int sq = t & 7;
    const int c0 = t >> 3;               // 0..31
#pragma unroll
    for (int p = 0; p < 4; ++p) {
        const int c  = c0 + 32 * p;
        const int co = (((c >> 2) ^ sq) << 2) + (c & 3);   // un-swizzled col
        vfloat4 v;
        v.x = tile[(4 * sq + 0) * CC + co];
        v.y = tile[(4 * sq + 1) * CC + co];
        v.z = tile[(4 * sq + 2) * CC + co];
        v.w = tile[(4 * sq + 3) * CC + co];
        __builtin_nontemporal_store(
            v, (vfloat4*)(out_feat + (((size_t)(b * CC + c) * KK + k) * SS + 4 * sq)));
    }

    if (t < 24) {
        const int d   = t >> 3;
        const int sq2 = t & 7;
        const vfloat4 v = *(vfloat4*)&txyz[d][4 * sq2];
        __builtin_nontemporal_store(
            v, (vfloat4*)(out_xyz + (((size_t)(b * 3 + d) * KK + k) * SS + 4 * sq2)));
    }
}

extern "C" void kernel_launch(void* const* d_in, const int* in_sizes, int n_in,
                              void* d_out, int out_size, void* d_ws, size_t ws_size,
                              hipStream_t stream) {
    const float* xyz     = (const float*)d_in[0];   // [2][16384][3]
    const float* new_xyz = (const float*)d_in[1];   // [2][4096][3]
    const float* feat    = (const float*)d_in[2];   // [2][128][16384]
    float* out = (float*)d_out;

    // Workspace: idx_buf 1MB | xyzw 0.5MB | feat_t 16MB | qmap 32KB
    int*   idx_buf = (int*)d_ws;
    float* xyzw    = (float*)((char*)d_ws + (1 << 20));
    float* feat_t  = (float*)((char*)d_ws + (1 << 20) + (512 << 10));
    int*   qmap    = (int*)((char*)d_ws + (1 << 20) + (512 << 10) + (CC * NN * BB) * 4);

    transpose_prep_kernel<<<dim3(BB * (NN / 64)), dim3(256), 0, stream>>>(
        feat, xyz, feat_t, xyzw);

    qsort_kernel<<<dim3(1), dim3(1024), 0, stream>>>(new_xyz, qmap);

    ball_query_kernel<<<dim3(BKK / 4), dim3(256), 0, stream>>>(
        xyzw, new_xyz, qmap, idx_buf);

    group_kernel<<<dim3(BKK), dim3(256), 0, stream>>>(
        xyzw, new_xyz, feat_t, idx_buf, out);
}

// Round 20
// 82.669 us; speedup vs baseline: 1.5344x; 1.1140x over previous
//
#include <hip/hip_runtime.h>

#define BB 2
#define NN 16384
#define KK 4096
#define CC 128
#define SS 32
#define BKK (BB * KK)

typedef float vfloat4 __attribute__((ext_vector_type(4)));

// ---------------------------------------------------------------------------
// Kernel 1: prep + sort, fused across blocks (33 blocks x 1024 threads).
// Block 0: r14 counting sort (1-LEVEL key, champion-verified; 2-level was
// only needed for the reverted v5/v6 and is unproven-neutral at best).
// Blocks 1-32: xyzw[b][n] = {x,y,z,|p|^2} prep (exact reference float exprs,
// absmax 0.0 rounds 2-19). The two are independent; fusing kills the
// 255-idle-CU window qsort had as a standalone single-block launch.
// ---------------------------------------------------------------------------
__global__ __launch_bounds__(1024) void prep_sort_kernel(
    const float* __restrict__ xyz, const float* __restrict__ new_xyz,
    float* __restrict__ xyzw, int* __restrict__ qmap)
{
    const int t = threadIdx.x;

    if (blockIdx.x == 0) {
        // --- qsort (r14 verbatim) ---
        __shared__ int hist[64];
        __shared__ int base[64];
        __shared__ unsigned char bk[BKK];    // 8 KB

        if (t < 64) hist[t] = 0;
        __syncthreads();

#pragma unroll
        for (int c = 0; c < BKK / 1024; ++c) {
            const int q = c * 1024 + t;
            const float* p = new_xyz + (size_t)q * 3;
            const float qq = p[0] * p[0] + p[1] * p[1] + p[2] * p[2];
            int bkt = (int)(qq * 8.0f);
            bkt = bkt > 63 ? 63 : bkt;
            bk[q] = (unsigned char)bkt;
            atomicAdd(&hist[bkt], 1);
        }
        __syncthreads();

        if (t == 0) {
            int s = 0;
#pragma unroll
            for (int i = 0; i < 64; ++i) { base[i] = s; s += hist[i]; }
        }
        __syncthreads();

#pragma unroll
        for (int c = 0; c < BKK / 1024; ++c) {
            const int q = c * 1024 + t;
            const int pos = atomicAdd(&base[bk[q]], 1);
            qmap[pos] = q;
        }
    } else {
        // --- xyzw prep: 32 blocks x 1024 threads = 32768 points ---
        const int i = (blockIdx.x - 1) * 1024 + t;
        const float* p = xyz + (size_t)i * 3;
        const float x = p[0], y = p[1], z = p[2];
        const float pp = __fadd_rn(__fadd_rn(__fmul_rn(x, x), __fmul_rn(y, y)),
                                   __fmul_rn(z, z));
        vfloat4 v = {x, y, z, pp};
        *(vfloat4*)(xyzw + (size_t)i * 4) = v;
    }
}

// ---------------------------------------------------------------------------
// Kernel 2: ball query ∥ feature transpose, fused across blocks.
// Blocks 0..2047: CHAMPION r14 ball body verbatim (per-wave 256-pt scan,
// ~34us, L2/VALU-bound, HBM idle). Blocks 2048..3071: transpose with a
// 32-row tile — 17 KB LDS so 8 blocks/CU still fit -> ball keeps full
// 32-wave/CU occupancy (v6 lesson: never trade ball's TLP). Ball blocks
// dispatch FIRST; transpose backfills and its HBM stream hides under ball.
// ---------------------------------------------------------------------------
__global__ __launch_bounds__(256) void ball_transpose_kernel(
    const float* __restrict__ xyzw,      // [B][N][4]
    const float* __restrict__ new_xyz,   // [B][K][3]
    const int* __restrict__ qmap,        // [BKK]
    const float* __restrict__ feat,      // [B][C][N]
    int* __restrict__ idx_buf,           // [BKK][S]
    float* __restrict__ feat_t)          // [B][N][C]
{
    __shared__ float tile[32][133];      // 17 KB (transpose blocks only)

    const int t = threadIdx.x;

    if (blockIdx.x < BKK / 4) {
        // ------------------ ball query (champion, verbatim) ------------------
        const int wave = t >> 6;
        const int lane = t & 63;
        const int qi   = qmap[blockIdx.x * 4 + wave];
        const int b    = qi >> 12;                   // K = 4096
        const int k    = qi & (KK - 1);

        const float R2 = (float)(0.4 * 0.4);

        const float* q = new_xyz + (size_t)(b * KK + k) * 3;
        const float qx = q[0], qy = q[1], qz = q[2];
        const float qq = __fadd_rn(__fadd_rn(__fmul_rn(qx, qx), __fmul_rn(qy, qy)),
                                   __fmul_rn(qz, qz));

        const vfloat4* xw = (const vfloat4*)xyzw + (size_t)b * NN;
        int* out = idx_buf + (size_t)qi * SS;

        int cnt = 0;
        int first = -1;

        auto process = [&](int base, vfloat4 v) {
            const float dot = __fadd_rn(__fadd_rn(__fmul_rn(qx, v.x), __fmul_rn(qy, v.y)),
                                        __fmul_rn(qz, v.z));
            const float d2 = __fsub_rn(__fadd_rn(qq, v.w), __fmul_rn(2.0f, dot));
            const bool inball = d2 < R2;
            const unsigned long long mask = __ballot(inball);
            if (mask) {
                if (first < 0) first = base + (int)__builtin_ctzll(mask);
                if (inball) {
                    const int pos = cnt + __popcll(mask & ((1ull << lane) - 1ull));
                    if (pos < SS) out[pos] = base + lane;
                }
                cnt += __popcll(mask);
            }
        };

        vfloat4 v0 = xw[lane];
        vfloat4 v1 = xw[64 + lane];
        vfloat4 v2 = xw[128 + lane];
        vfloat4 v3 = xw[192 + lane];

        for (int base = 0; base < NN; base += 256) {
            const int nb = (base + 256 < NN) ? base + 256 : 0;   // clamp; unused
            vfloat4 u0 = xw[nb + lane];
            vfloat4 u1 = xw[nb + 64 + lane];
            vfloat4 u2 = xw[nb + 128 + lane];
            vfloat4 u3 = xw[nb + 192 + lane];

            process(base, v0);
            process(base + 64, v1);
            process(base + 128, v2);
            process(base + 192, v3);
            if (cnt >= SS) break;

            v0 = u0; v1 = u1; v2 = u2; v3 = u3;
        }

        const int fill = (first < 0) ? 0 : first;
        if (lane < SS && lane >= cnt) out[lane] = fill;
    } else {
        // ------------------ transpose, 32-row tile ------------------
        const int tb = blockIdx.x - BKK / 4;     // 0..1023
        const int b  = tb >> 9;                  // NN/32 = 512 tiles per batch
        const int n0 = (tb & 511) * 32;

        // Read: 1024 float4 loads (c 0..127, n4 0..28 step 4), 4 iters.
#pragma unroll
        for (int i = 0; i < 4; ++i) {
            const int li = i * 256 + t;
            const int c  = li >> 3;
            const int n4 = (li & 7) * 4;
            const vfloat4 v = *(const vfloat4*)(feat + ((size_t)b * CC + c) * NN + n0 + n4);
            tile[n4 + 0][c] = v.x;
            tile[n4 + 1][c] = v.y;
            tile[n4 + 2][c] = v.z;
            tile[n4 + 3][c] = v.w;
        }
        __syncthreads();

        // Write: 1024 float4 stores (n 0..31, c4 0..124 step 4), 4 iters.
#pragma unroll
        for (int i = 0; i < 4; ++i) {
            const int li = i * 256 + t;
            const int n  = li >> 5;
            const int c4 = (li & 31) * 4;
            vfloat4 v;
            v.x = tile[n][c4 + 0];
            v.y = tile[n][c4 + 1];
            v.z = tile[n][c4 + 2];
            v.w = tile[n][c4 + 3];
            *(vfloat4*)(feat_t + ((size_t)(b * NN + n0 + n)) * CC + c4) = v;
        }
    }
}

// ---------------------------------------------------------------------------
// Kernel 3: grouping. UNCHANGED single-copy form (G~7us gather + W~24us
// stores, 0 bank conflicts — validated round 10).
// ---------------------------------------------------------------------------
__global__ __launch_bounds__(256) void group_kernel(
    const float* __restrict__ xyzw,      // [B][N][4]
    const float* __restrict__ new_xyz,   // [B][K][3]
    const float* __restrict__ feat_t,    // [B][N][C]
    const int*   __restrict__ idx_buf,   // [B*K][S]
    float* __restrict__ out)             // [B][3][K][S] ++ [B][C][K][S]
{
    __shared__ float tile[SS * CC];      // 32 rows x 512B, linear, chunk-swizzled
    __shared__ float txyz[3][SS];

    const int t    = threadIdx.x;
    const int l    = t & 63;
    const int w    = t >> 6;             // wave 0..3
    const int bk   = blockIdx.x;
    const int b    = bk >> 12;
    const int k    = bk & (KK - 1);
    const int half = l >> 5;             // 0..1
    const int cl   = l & 31;             // chunk slot within row

#pragma unroll
    for (int p = 0; p < 4; ++p) {
        const int r = 8 * w + 2 * p;                 // wave-uniform row base
        const int s = r + half;
        const int n = idx_buf[bk * SS + s];
        const int chunk = cl ^ ((s >> 2) & 7);
        const float* src = feat_t + ((size_t)(b * NN + n)) * CC + 4 * chunk;
        __builtin_amdgcn_global_load_lds(
            (const __attribute__((address_space(1))) void*)src,
            (__attribute__((address_space(3))) void*)(tile + r * CC),
            16, 0, 0);
    }

    if (t < SS) {
        const int n = idx_buf[bk * SS + t];
        const float* q = new_xyz + (size_t)bk * 3;
        const vfloat4 wv = *((const vfloat4*)xyzw + (size_t)b * NN + n);
        txyz[0][t] = (wv.x - q[0]) / 0.4f;
        txyz[1][t] = (wv.y - q[1]) / 0.4f;
        txyz[2][t] = (wv.z - q[2]) / 0.4f;
    }

    __syncthreads();   // drains vmcnt(0): all DMAs + txyz visible

    float* out_xyz  = out;
    float* out_feat = out + (size_t)BB * 3 * KK * SS;

    const int sq = t & 7;
    const int c0 = t >> 3;               // 0..31
#pragma unroll
    for (int p = 0; p < 4; ++p) {
        const int c  = c0 + 32 * p;
        const int co = (((c >> 2) ^ sq) << 2) + (c & 3);   // un-swizzled col
        vfloat4 v;
        v.x = tile[(4 * sq + 0) * CC + co];
        v.y = tile[(4 * sq + 1) * CC + co];
        v.z = tile[(4 * sq + 2) * CC + co];
        v.w = tile[(4 * sq + 3) * CC + co];
        __builtin_nontemporal_store(
            v, (vfloat4*)(out_feat + (((size_t)(b * CC + c) * KK + k) * SS + 4 * sq)));
    }

    if (t < 24) {
        const int d   = t >> 3;
        const int sq2 = t & 7;
        const vfloat4 v = *(vfloat4*)&txyz[d][4 * sq2];
        __builtin_nontemporal_store(
            v, (vfloat4*)(out_xyz + (((size_t)(b * 3 + d) * KK + k) * SS + 4 * sq2)));
    }
}

extern "C" void kernel_launch(void* const* d_in, const int* in_sizes, int n_in,
                              void* d_out, int out_size, void* d_ws, size_t ws_size,
                              hipStream_t stream) {
    const float* xyz     = (const float*)d_in[0];   // [2][16384][3]
    const float* new_xyz = (const float*)d_in[1];   // [2][4096][3]
    const float* feat    = (const float*)d_in[2];   // [2][128][16384]
    float* out = (float*)d_out;

    // Workspace: idx_buf 1MB | xyzw 0.5MB | feat_t 16MB | qmap 32KB
    int*   idx_buf = (int*)d_ws;
    float* xyzw    = (float*)((char*)d_ws + (1 << 20));
    float* feat_t  = (float*)((char*)d_ws + (1 << 20) + (512 << 10));
    int*   qmap    = (int*)((char*)d_ws + (1 << 20) + (512 << 10) + (CC * NN * BB) * 4);

    // 1: prep (blocks 1-32) ∥ qsort (block 0)
    prep_sort_kernel<<<dim3(33), dim3(1024), 0, stream>>>(
        xyz, new_xyz, xyzw, qmap);

    // 2: ball (blocks 0-2047, dispatched first) ∥ transpose (blocks 2048-3071)
    ball_transpose_kernel<<<dim3(BKK / 4 + BB * (NN / 32)), dim3(256), 0, stream>>>(
        xyzw, new_xyz, qmap, feat, idx_buf, feat_t);

    // 3: group
    group_kernel<<<dim3(BKK), dim3(256), 0, stream>>>(
        xyzw, new_xyz, feat_t, idx_buf, out);
}